// Round 1
// baseline (448.617 us; speedup 1.0000x reference)
//
#include <hip/hip_runtime.h>
#include <hip/hip_bf16.h>
#include <stdint.h>

// Sizes fixed by the problem
#define B_N 4096
#define P_N 32
#define C_N 512
// label coefficient: 2/(ALPHA*NORM) = 2/20 = 0.1
#define LABC 0.1f

typedef float  floatx4 __attribute__((ext_vector_type(4)));
typedef __bf16 bf16x8  __attribute__((ext_vector_type(8)));

__device__ __forceinline__ unsigned short f2bf(float x) {
    return __builtin_bit_cast(unsigned short, __float2bfloat16(x));
}
__device__ __forceinline__ float bf2f(unsigned short b) {
    return __builtin_bit_cast(float, ((unsigned int)b) << 16);
}

__device__ __forceinline__ void bfly_reduce2(float& a, float& b) {
#pragma unroll
    for (int m = 1; m < 64; m <<= 1) {
        a += __shfl_xor(a, m, 64);
        b += __shfl_xor(b, m, 64);
    }
}
__device__ __forceinline__ void bfly_reduce1(float& a) {
#pragma unroll
    for (int m = 1; m < 64; m <<= 1) a += __shfl_xor(a, m, 64);
}

// ---------------- init: zero the 3 double accumulators ----------------
__global__ void k_init(double* acc) {
    if (threadIdx.x < 3) acc[threadIdx.x] = 0.0;
}

// ---------------- kernel 1: normalize feats -> bf16 ----------------
// 1 wave per row, 4 rows per block (256 threads)
__global__ __launch_bounds__(256) void k_norm_feats(const float* __restrict__ feats,
                                                    unsigned short* __restrict__ fb) {
    const int wave = threadIdx.x >> 6, lane = threadIdx.x & 63;
    const int row = blockIdx.x * 4 + wave;
    const float* src = feats + (size_t)row * C_N + lane * 8;
    float4 v0 = *(const float4*)src;
    float4 v1 = *(const float4*)(src + 4);
    float ss = v0.x*v0.x + v0.y*v0.y + v0.z*v0.z + v0.w*v0.w
             + v1.x*v1.x + v1.y*v1.y + v1.z*v1.z + v1.w*v1.w;
    bfly_reduce1(ss);
    const float inv = rsqrtf(fmaxf(ss, 1e-24f));
    unsigned short o[8];
    o[0] = f2bf(v0.x*inv); o[1] = f2bf(v0.y*inv); o[2] = f2bf(v0.z*inv); o[3] = f2bf(v0.w*inv);
    o[4] = f2bf(v1.x*inv); o[5] = f2bf(v1.y*inv); o[6] = f2bf(v1.z*inv); o[7] = f2bf(v1.w*inv);
    uint4 pk;
    pk.x = (unsigned)o[0] | ((unsigned)o[1] << 16);
    pk.y = (unsigned)o[2] | ((unsigned)o[3] << 16);
    pk.z = (unsigned)o[4] | ((unsigned)o[5] << 16);
    pk.w = (unsigned)o[6] | ((unsigned)o[7] << 16);
    *(uint4*)(fb + (size_t)row * C_N + lane * 8) = pk;
}

// ---------------- kernel 2: per-b  tt (MFMA) + it (fused in norm pass) ----------------
// 1 block (256 thr) per b. Streams pivot_features[b] (64 KB fp32) exactly once.
#define CH_STRIDE 33  // chunk stride in rows (pad 32->33 to spread LDS banks)
__global__ __launch_bounds__(256) void k_tt_it(const float* __restrict__ pf_g,
                                               const float* __restrict__ ps_g,
                                               const float* __restrict__ targets,
                                               const unsigned short* __restrict__ fb,
                                               double* __restrict__ acc) {
    __shared__ __align__(16) unsigned short pfs[64 * CH_STRIDE * 8]; // [chunk][row][8] bf16 bits
    __shared__ float psS[P_N];
    __shared__ float redT[4], redI[4];

    const int b = blockIdx.x;
    const int tid = threadIdx.x, wave = tid >> 6, lane = tid & 63;
    const int quad = lane >> 4, l15 = lane & 15;

    if (tid < P_N) psS[tid] = ps_g[b * P_N + tid];
    const float tb = targets[b];

    // f_bf16[b] -> 8 floats per lane (lane's k-slice, shared across the 8 rows this wave does)
    uint4 fraw = *(const uint4*)(fb + (size_t)b * C_N + lane * 8);
    const unsigned short* fbits = (const unsigned short*)&fraw;
    float fr[8];
#pragma unroll
    for (int j = 0; j < 8; ++j) fr[j] = bf2f(fbits[j]);

    float it_sum = 0.f;
    const float* base = pf_g + (size_t)b * P_N * C_N;

#pragma unroll
    for (int i = 0; i < 8; ++i) {
        const int r = wave * 8 + i;
        const float* src = base + r * C_N + lane * 8;
        float4 v0 = *(const float4*)src;
        float4 v1 = *(const float4*)(src + 4);
        float pv[8] = {v0.x, v0.y, v0.z, v0.w, v1.x, v1.y, v1.z, v1.w};
        float ss = 0.f, fd = 0.f;
#pragma unroll
        for (int j = 0; j < 8; ++j) { ss += pv[j]*pv[j]; fd += pv[j]*fr[j]; }
        bfly_reduce2(ss, fd);
        const float inv = rsqrtf(fmaxf(ss, 1e-24f));
        // write normalized bf16 row into chunked layout: chunk = lane (8 elems/chunk)
        unsigned short o[8];
#pragma unroll
        for (int j = 0; j < 8; ++j) o[j] = f2bf(pv[j] * inv);
        uint4 pk;
        pk.x = (unsigned)o[0] | ((unsigned)o[1] << 16);
        pk.y = (unsigned)o[2] | ((unsigned)o[3] << 16);
        pk.z = (unsigned)o[4] | ((unsigned)o[5] << 16);
        pk.w = (unsigned)o[6] | ((unsigned)o[7] << 16);
        *(uint4*)&pfs[((size_t)lane * CH_STRIDE + r) * 8] = pk;
        if (lane == 0) {
            const float lab = 1.f - LABC * fabsf(tb - ps_g[b * P_N + r]);
            it_sum += fabsf(fd * inv - lab);
        }
    }
    __syncthreads();

    // tt = pf_norm @ pf_norm^T via MFMA; 4 waves cover the 32x32 output (16x16 tile each)
    const int pt = (wave >> 1) * 16, qt = (wave & 1) * 16;
    floatx4 acc4 = {0.f, 0.f, 0.f, 0.f};
#pragma unroll
    for (int kk = 0; kk < 16; ++kk) {
        const int ch = kk * 4 + quad;
        bf16x8 a = __builtin_bit_cast(bf16x8, *(const uint4*)&pfs[((size_t)ch * CH_STRIDE + pt + l15) * 8]);
        bf16x8 bb = __builtin_bit_cast(bf16x8, *(const uint4*)&pfs[((size_t)ch * CH_STRIDE + qt + l15) * 8]);
        acc4 = __builtin_amdgcn_mfma_f32_16x16x32_bf16(a, bb, acc4, 0, 0, 0);
    }
    float tt_sum = 0.f;
#pragma unroll
    for (int r = 0; r < 4; ++r) {
        const int p = pt + quad * 4 + r;   // D: row = quad*4+reg
        const int q = qt + l15;            //    col = lane&15
        const float lab = 1.f - LABC * fabsf(psS[p] - psS[q]);
        tt_sum += fabsf(acc4[r] - lab);
    }

    bfly_reduce2(tt_sum, it_sum);
    if (lane == 0) { redT[wave] = tt_sum; redI[wave] = it_sum; }
    __syncthreads();
    if (tid == 0) {
        atomicAdd(&acc[1], (double)(redT[0] + redT[1] + redT[2] + redT[3]));
        atomicAdd(&acc[2], (double)(redI[0] + redI[1] + redI[2] + redI[3]));
    }
}

// ---------------- kernel 3: ii = f f^T (bf16 MFMA, 128x128 tiles, upper triangle) ----------------
#define APAD 130  // chunk stride in rows for the 128-row tiles
__global__ __launch_bounds__(256) void k_ii(const unsigned short* __restrict__ fb,
                                            const float* __restrict__ targets,
                                            double* __restrict__ acc) {
    const int bm = blockIdx.y, bn = blockIdx.x;
    if (bn < bm) return;
    __shared__ __align__(16) unsigned short As[4 * APAD * 8];
    __shared__ __align__(16) unsigned short Bs[4 * APAD * 8];
    __shared__ float tmS[128], tnS[128];
    __shared__ float red[4];

    const int tid = threadIdx.x, wave = tid >> 6, lane = tid & 63;
    const int quad = lane >> 4, l15 = lane & 15;
    const int wr = wave >> 1, wc = wave & 1;
    const int mbase = bm * 128, nbase = bn * 128;

    if (tid < 128) tmS[tid] = targets[mbase + tid];
    else           tnS[tid - 128] = targets[nbase + tid - 128];

    const int row = tid >> 1, half = tid & 1;
    const unsigned short* aSrc = fb + (size_t)(mbase + row) * C_N + half * 16;
    const unsigned short* bSrc = fb + (size_t)(nbase + row) * C_N + half * 16;
    const int c0 = half * 2, c1 = half * 2 + 1;

    floatx4 accv[16];
#pragma unroll
    for (int i = 0; i < 16; ++i) accv[i] = (floatx4){0.f, 0.f, 0.f, 0.f};

    // prefetch k-step 0
    uint4 a0 = *(const uint4*)(aSrc);
    uint4 a1 = *(const uint4*)(aSrc + 8);
    uint4 b0 = *(const uint4*)(bSrc);
    uint4 b1 = *(const uint4*)(bSrc + 8);

    for (int ks = 0; ks < 16; ++ks) {
        __syncthreads();
        *(uint4*)&As[((size_t)c0 * APAD + row) * 8] = a0;
        *(uint4*)&As[((size_t)c1 * APAD + row) * 8] = a1;
        *(uint4*)&Bs[((size_t)c0 * APAD + row) * 8] = b0;
        *(uint4*)&Bs[((size_t)c1 * APAD + row) * 8] = b1;
        __syncthreads();
        if (ks < 15) {  // prefetch next k-step while MFMAs run
            const int off = (ks + 1) * 32;
            a0 = *(const uint4*)(aSrc + off);
            a1 = *(const uint4*)(aSrc + off + 8);
            b0 = *(const uint4*)(bSrc + off);
            b1 = *(const uint4*)(bSrc + off + 8);
        }
        bf16x8 af[4], bfv[4];
#pragma unroll
        for (int t = 0; t < 4; ++t)
            af[t] = __builtin_bit_cast(bf16x8, *(const uint4*)&As[((size_t)quad * APAD + wr * 64 + t * 16 + l15) * 8]);
#pragma unroll
        for (int t = 0; t < 4; ++t)
            bfv[t] = __builtin_bit_cast(bf16x8, *(const uint4*)&Bs[((size_t)quad * APAD + wc * 64 + t * 16 + l15) * 8]);
#pragma unroll
        for (int ti = 0; ti < 4; ++ti)
#pragma unroll
            for (int tj = 0; tj < 4; ++tj)
                accv[ti * 4 + tj] = __builtin_amdgcn_mfma_f32_16x16x32_bf16(af[ti], bfv[tj], accv[ti * 4 + tj], 0, 0, 0);
    }

    float s = 0.f;
#pragma unroll
    for (int ti = 0; ti < 4; ++ti) {
#pragma unroll
        for (int tj = 0; tj < 4; ++tj) {
#pragma unroll
            for (int r = 0; r < 4; ++r) {
                const int p = wr * 64 + ti * 16 + quad * 4 + r;
                const int q = wc * 64 + tj * 16 + l15;
                const float lab = 1.f - LABC * fabsf(tmS[p] - tnS[q]);
                s += fabsf(accv[ti * 4 + tj][r] - lab);
            }
        }
    }
    if (bm != bn) s *= 2.f;  // off-diagonal blocks counted twice (symmetry)
    bfly_reduce1(s);
    if (lane == 0) red[wave] = s;
    __syncthreads();
    if (tid == 0) atomicAdd(&acc[0], (double)(red[0] + red[1] + red[2] + red[3]));
}

// ---------------- kernel 4: mae + finalize ----------------
__global__ __launch_bounds__(256) void k_final(const float* __restrict__ pred,
                                               const float* __restrict__ targ,
                                               const double* __restrict__ acc,
                                               float* __restrict__ out) {
    __shared__ float red[4];
    const int tid = threadIdx.x, wave = tid >> 6, lane = tid & 63;
    float s = 0.f;
    for (int i = tid; i < B_N; i += 256) s += fabsf(pred[i] - targ[i]);
    bfly_reduce1(s);
    if (lane == 0) red[wave] = s;
    __syncthreads();
    if (tid == 0) {
        const float mae = (red[0] + red[1] + red[2] + red[3]) * (1.f / B_N);
        out[0] = (float)(acc[0] / (double)((size_t)B_N * B_N));          // image_image
        out[1] = (float)(acc[1] / (double)((size_t)B_N * P_N * P_N));    // text_text
        out[2] = (float)(acc[2] / (double)((size_t)B_N * P_N));          // image_text
        out[3] = mae;                                                    // mae
    }
}

extern "C" void kernel_launch(void* const* d_in, const int* in_sizes, int n_in,
                              void* d_out, int out_size, void* d_ws, size_t ws_size,
                              hipStream_t stream) {
    const float* pred  = (const float*)d_in[0];  // (B,)
    const float* targ  = (const float*)d_in[1];  // (B,)
    const float* feats = (const float*)d_in[2];  // (B,C)
    const float* pf    = (const float*)d_in[3];  // (B,P,C)
    const float* ps    = (const float*)d_in[4];  // (B,P)
    float* out = (float*)d_out;

    double* acc = (double*)d_ws;                                  // 3 doubles
    unsigned short* fb = (unsigned short*)((char*)d_ws + 256);    // f_bf16: B*C bf16 = 4 MB

    k_init<<<1, 64, 0, stream>>>(acc);
    k_norm_feats<<<B_N / 4, 256, 0, stream>>>(feats, fb);
    k_tt_it<<<B_N, 256, 0, stream>>>(pf, ps, targ, fb, acc);
    k_ii<<<dim3(32, 32), 256, 0, stream>>>(fb, targ, acc);
    k_final<<<1, 256, 0, stream>>>(pred, targ, acc, out);
}

// Round 2
// 412.752 us; speedup vs baseline: 1.0869x; 1.0869x over previous
//
#include <hip/hip_runtime.h>
#include <hip/hip_bf16.h>
#include <stdint.h>

// Sizes fixed by the problem
#define B_N 4096
#define P_N 32
#define C_N 512
#define LABC 0.1f       // 2/(ALPHA*NORM)
#define N_II 528        // 33*32/2 upper-triangle 128x128 tiles of the 4096x4096 Gram

typedef float  floatx4 __attribute__((ext_vector_type(4)));
typedef __bf16 bf16x8  __attribute__((ext_vector_type(8)));

__device__ __forceinline__ unsigned short f2bf(float x) {
    return __builtin_bit_cast(unsigned short, __float2bfloat16(x));
}
__device__ __forceinline__ uint4 pack8(const float4& v0, const float4& v1) {
    uint4 pk;
    pk.x = (unsigned)f2bf(v0.x) | ((unsigned)f2bf(v0.y) << 16);
    pk.y = (unsigned)f2bf(v0.z) | ((unsigned)f2bf(v0.w) << 16);
    pk.z = (unsigned)f2bf(v1.x) | ((unsigned)f2bf(v1.y) << 16);
    pk.w = (unsigned)f2bf(v1.z) | ((unsigned)f2bf(v1.w) << 16);
    return pk;
}
__device__ __forceinline__ void bfly_reduce2(float& a, float& b) {
#pragma unroll
    for (int m = 1; m < 64; m <<= 1) {
        a += __shfl_xor(a, m, 64);
        b += __shfl_xor(b, m, 64);
    }
}
__device__ __forceinline__ void bfly_reduce1(float& a) {
#pragma unroll
    for (int m = 1; m < 64; m <<= 1) a += __shfl_xor(a, m, 64);
}

// ---------------- kernel A: normalize feats -> bf16, mae partials, zero acc ----------------
// 1 wave per row, 4 rows per block (256 threads), 1024 blocks
__global__ __launch_bounds__(256) void k_prep(const float* __restrict__ feats,
                                              const float* __restrict__ pred,
                                              const float* __restrict__ targ,
                                              unsigned short* __restrict__ fb,
                                              double* __restrict__ acc,
                                              float* __restrict__ maePart) {
    const int wave = threadIdx.x >> 6, lane = threadIdx.x & 63;
    const int row = blockIdx.x * 4 + wave;
    const float* src = feats + (size_t)row * C_N + lane * 8;
    float4 v0 = *(const float4*)src;
    float4 v1 = *(const float4*)(src + 4);
    float ss = v0.x*v0.x + v0.y*v0.y + v0.z*v0.z + v0.w*v0.w
             + v1.x*v1.x + v1.y*v1.y + v1.z*v1.z + v1.w*v1.w;
    bfly_reduce1(ss);
    const float inv = rsqrtf(fmaxf(ss, 1e-24f));
    float4 n0 = {v0.x*inv, v0.y*inv, v0.z*inv, v0.w*inv};
    float4 n1 = {v1.x*inv, v1.y*inv, v1.z*inv, v1.w*inv};
    *(uint4*)(fb + (size_t)row * C_N + lane * 8) = pack8(n0, n1);

    if (wave == 0) {  // mae partials for this block's 4 rows
        float v = 0.f;
        if (lane < 4) {
            const int r = blockIdx.x * 4 + lane;
            v = fabsf(pred[r] - targ[r]);
        }
        v += __shfl_xor(v, 1, 64);
        v += __shfl_xor(v, 2, 64);
        if (lane == 0) maePart[blockIdx.x] = v;
    }
    if (blockIdx.x == 0 && threadIdx.x < 3) acc[threadIdx.x] = 0.0;
}

// ---------------- kernel B: fused ii (blocks [0,528)) + tt/it (blocks [528, 528+4096)) ----------------
#define APAD 130
struct TTsm {
    unsigned short pfs[64 * 33 * 8];  // [chunk 0..63][row 0..32][8 bf16]; row 32 = f_norm
    float psS[P_N];
    float rdiag[P_N];
    float redT[4], redI[4];
};
struct IIsm {
    unsigned short As[4 * APAD * 8];
    unsigned short Bs[4 * APAD * 8];
    float tm[128], tn[128];
    float red[4];
};
union SMu { TTsm tt; IIsm ii; };

__global__ __launch_bounds__(256) void k_fused(const float* __restrict__ pf_g,
                                               const float* __restrict__ ps_g,
                                               const float* __restrict__ targets,
                                               const unsigned short* __restrict__ fb,
                                               double* __restrict__ acc) {
    __shared__ __align__(16) SMu sm;
    const int tid = threadIdx.x, wave = tid >> 6, lane = tid & 63;
    const int quad = lane >> 4, l15 = lane & 15;

    if (blockIdx.x < N_II) {
        // ================= image-image: 128x128 upper-triangle Gram tile =================
        IIsm& S = sm.ii;
        int bm = 0, rem = blockIdx.x;
        while (rem >= 32 - bm) { rem -= 32 - bm; ++bm; }
        const int bn = bm + rem;
        const int wr = wave >> 1, wc = wave & 1;
        const int mbase = bm * 128, nbase = bn * 128;

        if (tid < 128) S.tm[tid] = targets[mbase + tid];
        else           S.tn[tid - 128] = targets[nbase + tid - 128];

        const int row = tid >> 1, half = tid & 1;
        const unsigned short* aSrc = fb + (size_t)(mbase + row) * C_N + half * 16;
        const unsigned short* bSrc = fb + (size_t)(nbase + row) * C_N + half * 16;
        const int c0 = half * 2, c1 = half * 2 + 1;

        floatx4 accv[16];
#pragma unroll
        for (int i = 0; i < 16; ++i) accv[i] = (floatx4){0.f, 0.f, 0.f, 0.f};

        uint4 a0 = *(const uint4*)(aSrc);
        uint4 a1 = *(const uint4*)(aSrc + 8);
        uint4 b0 = *(const uint4*)(bSrc);
        uint4 b1 = *(const uint4*)(bSrc + 8);

        for (int ks = 0; ks < 16; ++ks) {
            __syncthreads();
            *(uint4*)&S.As[((size_t)c0 * APAD + row) * 8] = a0;
            *(uint4*)&S.As[((size_t)c1 * APAD + row) * 8] = a1;
            *(uint4*)&S.Bs[((size_t)c0 * APAD + row) * 8] = b0;
            *(uint4*)&S.Bs[((size_t)c1 * APAD + row) * 8] = b1;
            __syncthreads();
            if (ks < 15) {
                const int off = (ks + 1) * 32;
                a0 = *(const uint4*)(aSrc + off);
                a1 = *(const uint4*)(aSrc + off + 8);
                b0 = *(const uint4*)(bSrc + off);
                b1 = *(const uint4*)(bSrc + off + 8);
            }
            bf16x8 af[4], bfv[4];
#pragma unroll
            for (int t = 0; t < 4; ++t)
                af[t] = __builtin_bit_cast(bf16x8, *(const uint4*)&S.As[((size_t)quad * APAD + wr * 64 + t * 16 + l15) * 8]);
#pragma unroll
            for (int t = 0; t < 4; ++t)
                bfv[t] = __builtin_bit_cast(bf16x8, *(const uint4*)&S.Bs[((size_t)quad * APAD + wc * 64 + t * 16 + l15) * 8]);
#pragma unroll
            for (int ti = 0; ti < 4; ++ti)
#pragma unroll
                for (int tj = 0; tj < 4; ++tj)
                    accv[ti * 4 + tj] = __builtin_amdgcn_mfma_f32_16x16x32_bf16(af[ti], bfv[tj], accv[ti * 4 + tj], 0, 0, 0);
        }

        float s = 0.f;
#pragma unroll
        for (int ti = 0; ti < 4; ++ti)
#pragma unroll
            for (int tj = 0; tj < 4; ++tj)
#pragma unroll
                for (int r = 0; r < 4; ++r) {
                    const int p = wr * 64 + ti * 16 + quad * 4 + r;
                    const int q = wc * 64 + tj * 16 + l15;
                    const float lab = 1.f - LABC * fabsf(S.tm[p] - S.tn[q]);
                    s += fabsf(accv[ti * 4 + tj][r] - lab);
                }
        if (bm != bn) s *= 2.f;
        bfly_reduce1(s);
        if (lane == 0) S.red[wave] = s;
        __syncthreads();
        if (tid == 0) atomicAdd(&acc[0], (double)(S.red[0] + S.red[1] + S.red[2] + S.red[3]));
    } else {
        // ================= text-text + image-text for one b =================
        TTsm& S = sm.tt;
        const int b = blockIdx.x - N_II;

        if (tid < P_N) S.psS[tid] = ps_g[b * P_N + tid];
        const float tb = targets[b];

        const float* base = pf_g + (size_t)b * P_N * C_N;
#pragma unroll
        for (int i = 0; i < 8; ++i) {
            const int r = wave * 8 + i;
            const float* src = base + r * C_N + lane * 8;
            float4 v0 = *(const float4*)src;
            float4 v1 = *(const float4*)(src + 4);
            *(uint4*)&S.pfs[((size_t)lane * 33 + r) * 8] = pack8(v0, v1);
        }
        if (wave == 0) {  // f_norm row -> row 32
            uint4 f = *(const uint4*)(fb + (size_t)b * C_N + lane * 8);
            *(uint4*)&S.pfs[((size_t)lane * 33 + 32) * 8] = f;
        }
        __syncthreads();

        // Gram of raw-bf16 pf (4 tiles, one per wave) + f-row tiles on waves 0,1
        const int pt = (wave >> 1) * 16, qt = (wave & 1) * 16;
        const bool doF = (wave < 2);  // f-tile cols == qt for waves 0,1
        floatx4 acc4 = {0.f, 0.f, 0.f, 0.f};
        floatx4 accF = {0.f, 0.f, 0.f, 0.f};
        const uint4 zero4 = {0u, 0u, 0u, 0u};
#pragma unroll
        for (int kk = 0; kk < 16; ++kk) {
            const int ch = kk * 4 + quad;
            bf16x8 a = __builtin_bit_cast(bf16x8, *(const uint4*)&S.pfs[((size_t)ch * 33 + pt + l15) * 8]);
            bf16x8 bb = __builtin_bit_cast(bf16x8, *(const uint4*)&S.pfs[((size_t)ch * 33 + qt + l15) * 8]);
            acc4 = __builtin_amdgcn_mfma_f32_16x16x32_bf16(a, bb, acc4, 0, 0, 0);
            if (doF) {
                uint4 fr = *(const uint4*)&S.pfs[((size_t)ch * 33 + 32) * 8];  // broadcast read
                bf16x8 af = __builtin_bit_cast(bf16x8, (l15 == 0) ? fr : zero4);
                accF = __builtin_amdgcn_mfma_f32_16x16x32_bf16(af, bb, accF, 0, 0, 0);
            }
        }
        // diagonal -> rsqrt (tiles (0,0) wave0 and (16,16) wave3)
        if (pt == qt) {
            if ((l15 >> 2) == quad) S.rdiag[pt + l15] = rsqrtf(fmaxf(acc4[l15 & 3], 1e-24f));
        }
        __syncthreads();

        float tt_sum = 0.f, it_sum = 0.f;
#pragma unroll
        for (int r = 0; r < 4; ++r) {
            const int p = pt + quad * 4 + r;
            const int q = qt + l15;
            const float val = acc4[r] * S.rdiag[p] * S.rdiag[q];
            const float lab = 1.f - LABC * fabsf(S.psS[p] - S.psS[q]);
            tt_sum += fabsf(val - lab);
        }
        if (doF && quad == 0) {  // D row 0 of the f-tile: lanes quad==0, reg 0
            const int q = qt + l15;
            const float val = accF[0] * S.rdiag[q];
            const float lab = 1.f - LABC * fabsf(tb - S.psS[q]);
            it_sum = fabsf(val - lab);
        }
        bfly_reduce2(tt_sum, it_sum);
        if (lane == 0) { S.redT[wave] = tt_sum; S.redI[wave] = it_sum; }
        __syncthreads();
        if (tid == 0) {
            atomicAdd(&acc[1], (double)(S.redT[0] + S.redT[1] + S.redT[2] + S.redT[3]));
            atomicAdd(&acc[2], (double)(S.redI[0] + S.redI[1] + S.redI[2] + S.redI[3]));
        }
    }
}

// ---------------- kernel C: finalize ----------------
__global__ __launch_bounds__(256) void k_final(const double* __restrict__ acc,
                                               const float* __restrict__ maePart,
                                               float* __restrict__ out) {
    __shared__ float red[4];
    const int tid = threadIdx.x, wave = tid >> 6, lane = tid & 63;
    float s = maePart[tid] + maePart[tid + 256] + maePart[tid + 512] + maePart[tid + 768];
    bfly_reduce1(s);
    if (lane == 0) red[wave] = s;
    __syncthreads();
    if (tid == 0) {
        out[0] = (float)(acc[0] / (double)((size_t)B_N * B_N));        // image_image
        out[1] = (float)(acc[1] / (double)((size_t)B_N * P_N * P_N));  // text_text
        out[2] = (float)(acc[2] / (double)((size_t)B_N * P_N));        // image_text
        out[3] = (red[0] + red[1] + red[2] + red[3]) * (1.f / B_N);    // mae
    }
}

extern "C" void kernel_launch(void* const* d_in, const int* in_sizes, int n_in,
                              void* d_out, int out_size, void* d_ws, size_t ws_size,
                              hipStream_t stream) {
    const float* pred  = (const float*)d_in[0];  // (B,)
    const float* targ  = (const float*)d_in[1];  // (B,)
    const float* feats = (const float*)d_in[2];  // (B,C)
    const float* pf    = (const float*)d_in[3];  // (B,P,C)
    const float* ps    = (const float*)d_in[4];  // (B,P)
    float* out = (float*)d_out;

    double* acc         = (double*)d_ws;                               // 3 doubles
    float* maePart      = (float*)((char*)d_ws + 256);                 // 1024 floats
    unsigned short* fb  = (unsigned short*)((char*)d_ws + 8192);       // f_norm bf16: 4 MB

    k_prep<<<B_N / 4, 256, 0, stream>>>(feats, pred, targ, fb, acc, maePart);
    k_fused<<<N_II + B_N, 256, 0, stream>>>(pf, ps, targ, fb, acc);
    k_final<<<1, 256, 0, stream>>>(acc, maePart, out);
}

// Round 3
// 382.564 us; speedup vs baseline: 1.1727x; 1.0789x over previous
//
#include <hip/hip_runtime.h>
#include <hip/hip_bf16.h>
#include <stdint.h>

// Sizes fixed by the problem
#define B_N 4096
#define P_N 32
#define C_N 512
#define LABC 0.1f       // 2/(ALPHA*NORM)
#define N_II 528        // 33*32/2 upper-triangle 128x128 tiles of the 4096x4096 Gram
// Interleave ii blocks 1-in-9 through the grid so the compute-bound ii tiles
// overlap the memory-bound pf stream instead of running first in a burst.
#define GRID_TOTAL (N_II * 9)   // 4752; tt blocks = 4752-528-... (128 early-exit)

typedef float  floatx4 __attribute__((ext_vector_type(4)));
typedef __bf16 bf16x8  __attribute__((ext_vector_type(8)));

__device__ __forceinline__ unsigned short f2bf(float x) {
    return __builtin_bit_cast(unsigned short, __float2bfloat16(x));
}
__device__ __forceinline__ uint4 pack8(const float4& v0, const float4& v1) {
    uint4 pk;
    pk.x = (unsigned)f2bf(v0.x) | ((unsigned)f2bf(v0.y) << 16);
    pk.y = (unsigned)f2bf(v0.z) | ((unsigned)f2bf(v0.w) << 16);
    pk.z = (unsigned)f2bf(v1.x) | ((unsigned)f2bf(v1.y) << 16);
    pk.w = (unsigned)f2bf(v1.z) | ((unsigned)f2bf(v1.w) << 16);
    return pk;
}
__device__ __forceinline__ void bfly_reduce2(float& a, float& b) {
#pragma unroll
    for (int m = 1; m < 64; m <<= 1) {
        a += __shfl_xor(a, m, 64);
        b += __shfl_xor(b, m, 64);
    }
}
__device__ __forceinline__ void bfly_reduce1(float& a) {
#pragma unroll
    for (int m = 1; m < 64; m <<= 1) a += __shfl_xor(a, m, 64);
}

// acc slots on separate 64B cache lines: acc[0]=ii, acc[8]=tt, acc[16]=it
#define ACC_II 0
#define ACC_TT 8
#define ACC_IT 16

// ---------------- kernel A: normalize feats -> bf16, mae partials, zero acc ----------------
__global__ __launch_bounds__(256) void k_prep(const float* __restrict__ feats,
                                              const float* __restrict__ pred,
                                              const float* __restrict__ targ,
                                              unsigned short* __restrict__ fb,
                                              double* __restrict__ acc,
                                              float* __restrict__ maePart) {
    const int wave = threadIdx.x >> 6, lane = threadIdx.x & 63;
    const int row = blockIdx.x * 4 + wave;
    const float* src = feats + (size_t)row * C_N + lane * 8;
    float4 v0 = *(const float4*)src;
    float4 v1 = *(const float4*)(src + 4);
    float ss = v0.x*v0.x + v0.y*v0.y + v0.z*v0.z + v0.w*v0.w
             + v1.x*v1.x + v1.y*v1.y + v1.z*v1.z + v1.w*v1.w;
    bfly_reduce1(ss);
    const float inv = rsqrtf(fmaxf(ss, 1e-24f));
    float4 n0 = {v0.x*inv, v0.y*inv, v0.z*inv, v0.w*inv};
    float4 n1 = {v1.x*inv, v1.y*inv, v1.z*inv, v1.w*inv};
    *(uint4*)(fb + (size_t)row * C_N + lane * 8) = pack8(n0, n1);

    if (wave == 0) {  // mae partials for this block's 4 rows
        float v = 0.f;
        if (lane < 4) {
            const int r = blockIdx.x * 4 + lane;
            v = fabsf(pred[r] - targ[r]);
        }
        v += __shfl_xor(v, 1, 64);
        v += __shfl_xor(v, 2, 64);
        if (lane == 0) maePart[blockIdx.x] = v;
    }
    if (blockIdx.x == 0 && threadIdx.x < 24) acc[threadIdx.x] = 0.0;
}

// ---------------- kernel B: fused ii + tt/it, interleaved 1-in-9 ----------------
#define APAD 130
struct TTsm {
    unsigned short pfs[64 * 33 * 8];  // [chunk 0..63][row 0..32][8 bf16]; row 32 = f_norm
    float psS[P_N];
    float rdiag[P_N];
    float redT[4], redI[4];
};
struct IIsm {
    unsigned short As[4 * APAD * 8];
    unsigned short Bs[4 * APAD * 8];
    float tm[128], tn[128];
    float red[4];
};
union SMu { TTsm tt; IIsm ii; };

__global__ __launch_bounds__(256) void k_fused(const float* __restrict__ pf_g,
                                               const float* __restrict__ ps_g,
                                               const float* __restrict__ targets,
                                               const unsigned short* __restrict__ fb,
                                               double* __restrict__ acc) {
    __shared__ __align__(16) SMu sm;
    const int tid = threadIdx.x, wave = tid >> 6, lane = tid & 63;
    const int quad = lane >> 4, l15 = lane & 15;
    const int bid = blockIdx.x;
    const bool isII = (bid % 9) == 0;

    if (isII) {
        // ================= image-image: 128x128 upper-triangle Gram tile =================
        IIsm& S = sm.ii;
        int bm = 0, rem = bid / 9;
        while (rem >= 32 - bm) { rem -= 32 - bm; ++bm; }
        const int bn = bm + rem;
        const int wr = wave >> 1, wc = wave & 1;
        const int mbase = bm * 128, nbase = bn * 128;

        if (tid < 128) S.tm[tid] = targets[mbase + tid];
        else           S.tn[tid - 128] = targets[nbase + tid - 128];

        const int row = tid >> 1, half = tid & 1;
        const unsigned short* aSrc = fb + (size_t)(mbase + row) * C_N + half * 16;
        const unsigned short* bSrc = fb + (size_t)(nbase + row) * C_N + half * 16;
        const int c0 = half * 2, c1 = half * 2 + 1;

        floatx4 accv[16];
#pragma unroll
        for (int i = 0; i < 16; ++i) accv[i] = (floatx4){0.f, 0.f, 0.f, 0.f};

        uint4 a0 = *(const uint4*)(aSrc);
        uint4 a1 = *(const uint4*)(aSrc + 8);
        uint4 b0 = *(const uint4*)(bSrc);
        uint4 b1 = *(const uint4*)(bSrc + 8);

        for (int ks = 0; ks < 16; ++ks) {
            __syncthreads();
            *(uint4*)&S.As[((size_t)c0 * APAD + row) * 8] = a0;
            *(uint4*)&S.As[((size_t)c1 * APAD + row) * 8] = a1;
            *(uint4*)&S.Bs[((size_t)c0 * APAD + row) * 8] = b0;
            *(uint4*)&S.Bs[((size_t)c1 * APAD + row) * 8] = b1;
            __syncthreads();
            if (ks < 15) {
                const int off = (ks + 1) * 32;
                a0 = *(const uint4*)(aSrc + off);
                a1 = *(const uint4*)(aSrc + off + 8);
                b0 = *(const uint4*)(bSrc + off);
                b1 = *(const uint4*)(bSrc + off + 8);
            }
            bf16x8 af[4], bfv[4];
#pragma unroll
            for (int t = 0; t < 4; ++t)
                af[t] = __builtin_bit_cast(bf16x8, *(const uint4*)&S.As[((size_t)quad * APAD + wr * 64 + t * 16 + l15) * 8]);
#pragma unroll
            for (int t = 0; t < 4; ++t)
                bfv[t] = __builtin_bit_cast(bf16x8, *(const uint4*)&S.Bs[((size_t)quad * APAD + wc * 64 + t * 16 + l15) * 8]);
#pragma unroll
            for (int ti = 0; ti < 4; ++ti)
#pragma unroll
                for (int tj = 0; tj < 4; ++tj)
                    accv[ti * 4 + tj] = __builtin_amdgcn_mfma_f32_16x16x32_bf16(af[ti], bfv[tj], accv[ti * 4 + tj], 0, 0, 0);
        }

        float s = 0.f;
#pragma unroll
        for (int ti = 0; ti < 4; ++ti)
#pragma unroll
            for (int tj = 0; tj < 4; ++tj)
#pragma unroll
                for (int r = 0; r < 4; ++r) {
                    const int p = wr * 64 + ti * 16 + quad * 4 + r;
                    const int q = wc * 64 + tj * 16 + l15;
                    const float lab = 1.f - LABC * fabsf(S.tm[p] - S.tn[q]);
                    s += fabsf(accv[ti * 4 + tj][r] - lab);
                }
        if (bm != bn) s *= 2.f;
        bfly_reduce1(s);
        if (lane == 0) S.red[wave] = s;
        __syncthreads();
        if (tid == 0) atomicAdd(&acc[ACC_II], (double)(S.red[0] + S.red[1] + S.red[2] + S.red[3]));
    } else {
        // ================= text-text + image-text for one b =================
        const int b = bid - (bid / 9) - 1;
        if (b >= B_N) return;
        TTsm& S = sm.tt;

        if (tid < P_N) S.psS[tid] = ps_g[b * P_N + tid];
        const float tb = targets[b];

        const float* base = pf_g + (size_t)b * P_N * C_N;
#pragma unroll
        for (int i = 0; i < 8; ++i) {
            const int r = wave * 8 + i;
            const float* src = base + r * C_N + lane * 8;
            float4 v0 = *(const float4*)src;
            float4 v1 = *(const float4*)(src + 4);
            *(uint4*)&S.pfs[((size_t)lane * 33 + r) * 8] = pack8(v0, v1);
        }
        if (wave == 0) {  // f_norm row -> row 32
            uint4 f = *(const uint4*)(fb + (size_t)b * C_N + lane * 8);
            *(uint4*)&S.pfs[((size_t)lane * 33 + 32) * 8] = f;
        }
        __syncthreads();

        // Gram of raw-bf16 pf (4 tiles, one per wave) + f-row tiles on waves 0,1
        const int pt = (wave >> 1) * 16, qt = (wave & 1) * 16;
        const bool doF = (wave < 2);  // f-tile cols == qt for waves 0,1
        floatx4 acc4 = {0.f, 0.f, 0.f, 0.f};
        floatx4 accF = {0.f, 0.f, 0.f, 0.f};
        const uint4 zero4 = {0u, 0u, 0u, 0u};
#pragma unroll
        for (int kk = 0; kk < 16; ++kk) {
            const int ch = kk * 4 + quad;
            bf16x8 a = __builtin_bit_cast(bf16x8, *(const uint4*)&S.pfs[((size_t)ch * 33 + pt + l15) * 8]);
            bf16x8 bb = __builtin_bit_cast(bf16x8, *(const uint4*)&S.pfs[((size_t)ch * 33 + qt + l15) * 8]);
            acc4 = __builtin_amdgcn_mfma_f32_16x16x32_bf16(a, bb, acc4, 0, 0, 0);
            if (doF) {
                uint4 fr = *(const uint4*)&S.pfs[((size_t)ch * 33 + 32) * 8];  // broadcast read
                bf16x8 af = __builtin_bit_cast(bf16x8, (l15 == 0) ? fr : zero4);
                accF = __builtin_amdgcn_mfma_f32_16x16x32_bf16(af, bb, accF, 0, 0, 0);
            }
        }
        // diagonal -> rsqrt (tiles (0,0) wave0 and (16,16) wave3)
        if (pt == qt) {
            if ((l15 >> 2) == quad) S.rdiag[pt + l15] = rsqrtf(fmaxf(acc4[l15 & 3], 1e-24f));
        }
        __syncthreads();

        float tt_sum = 0.f, it_sum = 0.f;
#pragma unroll
        for (int r = 0; r < 4; ++r) {
            const int p = pt + quad * 4 + r;
            const int q = qt + l15;
            const float val = acc4[r] * S.rdiag[p] * S.rdiag[q];
            const float lab = 1.f - LABC * fabsf(S.psS[p] - S.psS[q]);
            tt_sum += fabsf(val - lab);
        }
        if (doF && quad == 0) {  // D row 0 of the f-tile: lanes quad==0, reg 0
            const int q = qt + l15;
            const float val = accF[0] * S.rdiag[q];
            const float lab = 1.f - LABC * fabsf(tb - S.psS[q]);
            it_sum = fabsf(val - lab);
        }
        bfly_reduce2(tt_sum, it_sum);
        if (lane == 0) { S.redT[wave] = tt_sum; S.redI[wave] = it_sum; }
        __syncthreads();
        if (tid == 0) {
            atomicAdd(&acc[ACC_TT], (double)(S.redT[0] + S.redT[1] + S.redT[2] + S.redT[3]));
            atomicAdd(&acc[ACC_IT], (double)(S.redI[0] + S.redI[1] + S.redI[2] + S.redI[3]));
        }
    }
}

// ---------------- kernel C: finalize ----------------
__global__ __launch_bounds__(256) void k_final(const double* __restrict__ acc,
                                               const float* __restrict__ maePart,
                                               float* __restrict__ out) {
    __shared__ float red[4];
    const int tid = threadIdx.x, wave = tid >> 6, lane = tid & 63;
    float s = maePart[tid] + maePart[tid + 256] + maePart[tid + 512] + maePart[tid + 768];
    bfly_reduce1(s);
    if (lane == 0) red[wave] = s;
    __syncthreads();
    if (tid == 0) {
        out[0] = (float)(acc[ACC_II] / (double)((size_t)B_N * B_N));        // image_image
        out[1] = (float)(acc[ACC_TT] / (double)((size_t)B_N * P_N * P_N));  // text_text
        out[2] = (float)(acc[ACC_IT] / (double)((size_t)B_N * P_N));        // image_text
        out[3] = (red[0] + red[1] + red[2] + red[3]) * (1.f / B_N);         // mae
    }
}

extern "C" void kernel_launch(void* const* d_in, const int* in_sizes, int n_in,
                              void* d_out, int out_size, void* d_ws, size_t ws_size,
                              hipStream_t stream) {
    const float* pred  = (const float*)d_in[0];  // (B,)
    const float* targ  = (const float*)d_in[1];  // (B,)
    const float* feats = (const float*)d_in[2];  // (B,C)
    const float* pf    = (const float*)d_in[3];  // (B,P,C)
    const float* ps    = (const float*)d_in[4];  // (B,P)
    float* out = (float*)d_out;

    double* acc         = (double*)d_ws;                               // 24 doubles (3 used, 64B apart)
    float* maePart      = (float*)((char*)d_ws + 256);                 // 1024 floats
    unsigned short* fb  = (unsigned short*)((char*)d_ws + 8192);       // f_norm bf16: 4 MB

    k_prep<<<B_N / 4, 256, 0, stream>>>(feats, pred, targ, fb, acc, maePart);
    k_fused<<<GRID_TOTAL, 256, 0, stream>>>(pf, ps, targ, fb, acc);
    k_final<<<1, 256, 0, stream>>>(acc, maePart, out);
}